// Round 5
// baseline (232.515 us; speedup 1.0000x reference)
//
#include <hip/hip_runtime.h>

// RoIAlign: features (2,256,200,304) fp32 NCHW, rois (512,5) fp32,
// out (512,256,7,7) fp32. OUT=7x7, sampling ratio G=2, scale 0.25.
//
// Round 12: gather blocks merged along ph: one block handles an roi's
// ph-row PAIR ({0,1},{2,3},{4,5},{6}) -> 2048 blocks (was 3584). r10
// measured per-block fixed cost ~4.5ns (adding 3584 blocks cost +16us);
// merging recovers ~7us of that, and the epilogue becomes 56-B contiguous
// per channel (rows ph,ph+1 adjacent in output). Body = r11 (uint2 x 64
// threads, compile-time unrolled corner loads, now up to 224/wave -> more
// MLP). pair==3 (row 6) takes the 28-sample branch (block-uniform).
// All accumulator indexing compile-time (r9 lesson: never runtime-index).
// Transpose = round-8 (512-B bursts, at HBM floor), unchanged.

#define OUT_H 7
#define OUT_W 7
constexpr float SPATIAL_SCALE = 0.25f;
constexpr int CN = 256;   // channels
constexpr int FH = 200;
constexpr int FW = 304;
constexpr int N_IMG = 2;
constexpr int N_ROIS = 512;
constexpr int PIX = FH * FW;               // 60800 = 475 * 128
constexpr size_t PLANE = (size_t)PIX;
constexpr size_t NHWC_ELEMS = (size_t)N_IMG * PLANE * CN;
constexpr size_t NHWC_BF16_BYTES = NHWC_ELEMS * sizeof(unsigned short);

constexpr int CT = 64;    // channel tile
constexpr int PT = 128;   // pixel tile (60800 % 128 == 0)

__device__ __forceinline__ unsigned short f2bf_rne(float f) {
    unsigned int u = __float_as_uint(f);
    unsigned int r = (u + 0x7FFFu + ((u >> 16) & 1u)) >> 16;  // RNE
    return (unsigned short)r;
}

// ---------------- tiled transpose NCHW fp32 -> NHWC bf16 ----------------
// grid (PIX/PT = 475, N_IMG*CN/CT = 8), 256 threads.
// Phase 1: thread (q = t&31, r = t>>5) loads float4 of channel c = r + 8i
//   at pixel offset 4q. Per wave instruction (fixed i): 2 x 512-B bursts.
// Phase 2: thread (cq = t&7, p0 = t>>3) packs 8 channels -> uint4 at
//   pixel p = p0 + 32*i2; full-128B-line NHWC writes. Row stride 129
//   keeps phase-2 LDS reads at 2 lanes/bank (free).
__global__ __launch_bounds__(256) void nchw_to_nhwc_bf16_tiled(
    const float* __restrict__ in, unsigned short* __restrict__ ws)
{
    const int pbase = blockIdx.x * PT;
    const int nc = blockIdx.y;           // 0..7
    const int n = nc >> 2;
    const int cbase = (nc & 3) * CT;

    __shared__ float tile[CT][PT + 1];   // 64 x 129 fp32 = 33,024 B

    {
        const int q = threadIdx.x & 31;  // float4 slot within pixel row
        const int r = threadIdx.x >> 5;  // 0..7
        const float* src = in + ((size_t)n * CN + cbase) * PLANE + pbase + 4 * q;
#pragma unroll
        for (int i = 0; i < 8; ++i) {
            const int c = r + 8 * i;
            const float4 v = *(const float4*)(src + (size_t)c * PLANE);
            tile[c][4 * q + 0] = v.x;
            tile[c][4 * q + 1] = v.y;
            tile[c][4 * q + 2] = v.z;
            tile[c][4 * q + 3] = v.w;
        }
    }
    __syncthreads();
    {
        const int cq = threadIdx.x & 7;  // channel octet: channels 8cq..8cq+7
        const int p0 = threadIdx.x >> 3; // 0..31
        unsigned short* dstbase =
            ws + ((size_t)n * PLANE + pbase) * CN + cbase + 8 * cq;
#pragma unroll
        for (int i2 = 0; i2 < 4; ++i2) {
            const int p = p0 + 32 * i2;
            uint4 pk;
            pk.x = (unsigned int)f2bf_rne(tile[8 * cq + 0][p]) |
                   ((unsigned int)f2bf_rne(tile[8 * cq + 1][p]) << 16);
            pk.y = (unsigned int)f2bf_rne(tile[8 * cq + 2][p]) |
                   ((unsigned int)f2bf_rne(tile[8 * cq + 3][p]) << 16);
            pk.z = (unsigned int)f2bf_rne(tile[8 * cq + 4][p]) |
                   ((unsigned int)f2bf_rne(tile[8 * cq + 5][p]) << 16);
            pk.w = (unsigned int)f2bf_rne(tile[8 * cq + 6][p]) |
                   ((unsigned int)f2bf_rne(tile[8 * cq + 7][p]) << 16);
            *(uint4*)(dstbase + (size_t)p * CN) = pk;
        }
    }
}

// ---------------- gather on NHWC bf16: (roi, ph-pair) blocks -------------
// 1-D grid of 2048; decode so all 4 blocks of a roi share (id % 8) =>
// same XCD. pair p in {0,1,2}: rows 2p,2p+1 (56 samples, 224 loads);
// pair 3: row 6 (28 samples). One wave; thread t owns channels 4t..4t+3.
__global__ __launch_bounds__(64) void roi_align_nhwc_bf16(
    const unsigned short* __restrict__ ws,
    const float* __restrict__ rois,
    float* __restrict__ out)
{
    const int b = blockIdx.x;
    const int x = b & 7;                 // XCD residue
    const int sid = b >> 3;              // 0..255
    const int r    = (sid >> 2) * 8 + x; // roi
    const int pair = sid & 3;
    const int ph0  = 2 * pair;           // 0,2,4,6
    const int t  = threadIdx.x;          // channel quad: 4t..4t+3

    __shared__ float s_roi[5];
    __shared__ int   s_off[56][4];       // BYTE offsets into NHWC bf16 image
    __shared__ float s_w[56][4];
    __shared__ int   s_b;

    if (t < 5) s_roi[t] = rois[r * 5 + t];
    __syncthreads();

    const int NS = (pair < 3) ? 56 : 28;
    if (t < NS) {
        const int row = t / 28;          // 0 or 1
        const int ss  = t % 28;
        const int gy = ss / 14;
        const int ix = ss % 14;
        const int ph = ph0 + row;
        const float x1 = s_roi[1] * SPATIAL_SCALE - 0.5f;
        const float y1 = s_roi[2] * SPATIAL_SCALE - 0.5f;
        const float x2 = s_roi[3] * SPATIAL_SCALE - 0.5f;
        const float y2 = s_roi[4] * SPATIAL_SCALE - 0.5f;
        const float bin_w = (x2 - x1) / OUT_W;
        const float bin_h = (y2 - y1) / OUT_H;
        const float y = y1 + ph * bin_h + (gy + 0.5f) * bin_h * 0.5f;
        const float xf = x1 + (ix >> 1) * bin_w + ((ix & 1) + 0.5f) * bin_w * 0.5f;
        const float validf =
            (y > -1.0f && y < (float)FH && xf > -1.0f && xf < (float)FW) ? 1.0f : 0.0f;
        const float yc = fminf(fmaxf(y, 0.0f), (float)(FH - 1));
        const float xc = fminf(fmaxf(xf, 0.0f), (float)(FW - 1));
        const int y0 = (int)floorf(yc);
        const int x0 = (int)floorf(xc);
        const int y1i = min(y0 + 1, FH - 1);
        const int x1i = min(x0 + 1, FW - 1);
        const float ly = yc - (float)y0;
        const float lx = xc - (float)x0;
        const float hy = 1.0f - ly;
        const float hx = 1.0f - lx;
        s_off[t][0] = ((y0  * FW + x0 ) * CN) * 2;
        s_off[t][1] = ((y0  * FW + x1i) * CN) * 2;
        s_off[t][2] = ((y1i * FW + x0 ) * CN) * 2;
        s_off[t][3] = ((y1i * FW + x1i) * CN) * 2;
        s_w[t][0] = hy * hx * validf;
        s_w[t][1] = hy * lx * validf;
        s_w[t][2] = ly * hx * validf;
        s_w[t][3] = ly * lx * validf;
    }
    if (t == 0) s_b = (int)s_roi[0];
    __syncthreads();

    const char* base =
        (const char*)(ws + (size_t)s_b * (PLANE * CN)) + 8 * t;

    // acc index: row*7 + pw (compile-time in both unrolled branches)
    float acc0[14] = {0.f,0.f,0.f,0.f,0.f,0.f,0.f,0.f,0.f,0.f,0.f,0.f,0.f,0.f};
    float acc1[14] = {0.f,0.f,0.f,0.f,0.f,0.f,0.f,0.f,0.f,0.f,0.f,0.f,0.f,0.f};
    float acc2[14] = {0.f,0.f,0.f,0.f,0.f,0.f,0.f,0.f,0.f,0.f,0.f,0.f,0.f,0.f};
    float acc3[14] = {0.f,0.f,0.f,0.f,0.f,0.f,0.f,0.f,0.f,0.f,0.f,0.f,0.f,0.f};

    if (pair < 3) {
#pragma unroll
        for (int s = 0; s < 56; ++s) {
            const int ai = (s / 28) * 7 + (((s % 28) % 14) >> 1);
#pragma unroll
            for (int k = 0; k < 4; ++k) {
                const uint2 u = *(const uint2*)(base + s_off[s][k]);
                const float f0 = __uint_as_float(u.x << 16);
                const float f1 = __uint_as_float(u.x & 0xFFFF0000u);
                const float f2 = __uint_as_float(u.y << 16);
                const float f3 = __uint_as_float(u.y & 0xFFFF0000u);
                const float w = s_w[s][k];
                acc0[ai] = fmaf(w, f0, acc0[ai]);
                acc1[ai] = fmaf(w, f1, acc1[ai]);
                acc2[ai] = fmaf(w, f2, acc2[ai]);
                acc3[ai] = fmaf(w, f3, acc3[ai]);
            }
        }
    } else {
#pragma unroll
        for (int s = 0; s < 28; ++s) {
            const int ai = (s % 14) >> 1;
#pragma unroll
            for (int k = 0; k < 4; ++k) {
                const uint2 u = *(const uint2*)(base + s_off[s][k]);
                const float f0 = __uint_as_float(u.x << 16);
                const float f1 = __uint_as_float(u.x & 0xFFFF0000u);
                const float f2 = __uint_as_float(u.y << 16);
                const float f3 = __uint_as_float(u.y & 0xFFFF0000u);
                const float w = s_w[s][k];
                acc0[ai] = fmaf(w, f0, acc0[ai]);
                acc1[ai] = fmaf(w, f1, acc1[ai]);
                acc2[ai] = fmaf(w, f2, acc2[ai]);
                acc3[ai] = fmaf(w, f3, acc3[ai]);
            }
        }
    }

    // rows ph0 (+ph0+1) are contiguous in output: 14 (or 7) floats/channel
    constexpr int OHW = OUT_H * OUT_W;   // 49
    const size_t outbase = ((size_t)r * CN + 4 * t) * OHW + (size_t)ph0 * OUT_W;
    if (pair < 3) {
#pragma unroll
        for (int i = 0; i < 14; ++i) {
            out[outbase + 0 * OHW + i] = acc0[i] * 0.25f;
            out[outbase + 1 * OHW + i] = acc1[i] * 0.25f;
            out[outbase + 2 * OHW + i] = acc2[i] * 0.25f;
            out[outbase + 3 * OHW + i] = acc3[i] * 0.25f;
        }
    } else {
#pragma unroll
        for (int i = 0; i < 7; ++i) {
            out[outbase + 0 * OHW + i] = acc0[i] * 0.25f;
            out[outbase + 1 * OHW + i] = acc1[i] * 0.25f;
            out[outbase + 2 * OHW + i] = acc2[i] * 0.25f;
            out[outbase + 3 * OHW + i] = acc3[i] * 0.25f;
        }
    }
}

// ---------------- fallback: NCHW gather (round-1 kernel) ----------------
__global__ __launch_bounds__(256) void roi_align_nchw(
    const float* __restrict__ feat,
    const float* __restrict__ rois,
    float* __restrict__ out)
{
    const int r  = blockIdx.x;
    const int ph = blockIdx.y;
    const int c  = threadIdx.x;

    __shared__ float s_roi[5];
    __shared__ int   s_off[28][4];
    __shared__ float s_w[28][4];
    __shared__ int   s_b;

    if (threadIdx.x < 5) s_roi[threadIdx.x] = rois[r * 5 + threadIdx.x];
    __syncthreads();

    if (threadIdx.x < 28) {
        const int s  = threadIdx.x;
        const int gy = s / 14;
        const int ix = s % 14;
        const float x1 = s_roi[1] * SPATIAL_SCALE - 0.5f;
        const float y1 = s_roi[2] * SPATIAL_SCALE - 0.5f;
        const float x2 = s_roi[3] * SPATIAL_SCALE - 0.5f;
        const float y2 = s_roi[4] * SPATIAL_SCALE - 0.5f;
        const float bin_w = (x2 - x1) / OUT_W;
        const float bin_h = (y2 - y1) / OUT_H;
        const float y = y1 + ph * bin_h + (gy + 0.5f) * bin_h * 0.5f;
        const float xf = x1 + (ix >> 1) * bin_w + ((ix & 1) + 0.5f) * bin_w * 0.5f;
        const float validf =
            (y > -1.0f && y < (float)FH && xf > -1.0f && xf < (float)FW) ? 1.0f : 0.0f;
        const float yc = fminf(fmaxf(y, 0.0f), (float)(FH - 1));
        const float xc = fminf(fmaxf(xf, 0.0f), (float)(FW - 1));
        const int y0 = (int)floorf(yc);
        const int x0 = (int)floorf(xc);
        const int y1i = min(y0 + 1, FH - 1);
        const int x1i = min(x0 + 1, FW - 1);
        const float ly = yc - (float)y0;
        const float lx = xc - (float)x0;
        const float hy = 1.0f - ly;
        const float hx = 1.0f - lx;
        s_off[s][0] = y0  * FW + x0;
        s_off[s][1] = y0  * FW + x1i;
        s_off[s][2] = y1i * FW + x0;
        s_off[s][3] = y1i * FW + x1i;
        s_w[s][0] = hy * hx * validf;
        s_w[s][1] = hy * lx * validf;
        s_w[s][2] = ly * hx * validf;
        s_w[s][3] = ly * lx * validf;
    }
    if (threadIdx.x == 0) s_b = (int)s_roi[0];
    __syncthreads();

    const float* base = feat + ((size_t)s_b * CN + c) * PLANE;

    float acc[OUT_W] = {0.f, 0.f, 0.f, 0.f, 0.f, 0.f, 0.f};
#pragma unroll
    for (int s = 0; s < 28; ++s) {
        const float v0 = base[s_off[s][0]];
        const float v1 = base[s_off[s][1]];
        const float v2 = base[s_off[s][2]];
        const float v3 = base[s_off[s][3]];
        acc[(s % 14) >> 1] += s_w[s][0] * v0 + s_w[s][1] * v1 +
                              s_w[s][2] * v2 + s_w[s][3] * v3;
    }

    const size_t outbase = ((size_t)r * CN + c) * (OUT_H * OUT_W) + (size_t)ph * OUT_W;
#pragma unroll
    for (int pw = 0; pw < OUT_W; ++pw) {
        out[outbase + pw] = acc[pw] * 0.25f;
    }
}

extern "C" void kernel_launch(void* const* d_in, const int* in_sizes, int n_in,
                              void* d_out, int out_size, void* d_ws, size_t ws_size,
                              hipStream_t stream) {
    const float* feat = (const float*)d_in[0];
    const float* rois = (const float*)d_in[1];
    float* out = (float*)d_out;

    if (ws_size >= NHWC_BF16_BYTES) {
        unsigned short* ws = (unsigned short*)d_ws;
        dim3 tgrid(PIX / PT, (N_IMG * CN) / CT, 1);  // 475 x 8 = 3800 blocks
        nchw_to_nhwc_bf16_tiled<<<tgrid, dim3(256, 1, 1), 0, stream>>>(feat, ws);
        roi_align_nhwc_bf16<<<dim3(N_ROIS * 4, 1, 1), dim3(64, 1, 1), 0, stream>>>(
            ws, rois, out);
    } else {
        dim3 grid(N_ROIS, OUT_H, 1);
        roi_align_nchw<<<grid, dim3(256, 1, 1), 0, stream>>>(feat, rois, out);
    }
}

// Round 6
// 219.308 us; speedup vs baseline: 1.0602x; 1.0602x over previous
//
#include <hip/hip_runtime.h>

// RoIAlign: features (2,256,200,304) fp32 NCHW, rois (512,5) fp32,
// out (512,256,7,7) fp32. OUT=7x7, sampling ratio G=2, scale 0.25.
//
// Round 13: REVERT to proven-best (round-8) configuration after the probe
// series. Session ledger, fill-normalized (dur - 2x fill):
//   r8  (this form):      218.4/218.65us, residual 62.6-65.4  <- best
//   r9  dedup:            +29us (runtime bounds killed MLP)
//   r10 pw-split:         +16us (halved per-wave work, fragmented stores)
//   r11 uint2/64thr:      neutral (issue rate is not the binding resource)
//   r12 ph-pair merge:    neutral (per-block prologue is not it either)
// Structural accounting: 2x498MB harness poison fills ~152us (fixed) +
// transpose ~32us (187MB at 6.3TB/s HBM floor, burst-insensitive per r8)
// + gather ~29us (latency floor at this access entropy; 4 structural
// variants within noise) + ~5us gaps = ~218us. At structural roofline.

#define OUT_H 7
#define OUT_W 7
constexpr float SPATIAL_SCALE = 0.25f;
constexpr int CN = 256;   // channels
constexpr int FH = 200;
constexpr int FW = 304;
constexpr int N_IMG = 2;
constexpr int N_ROIS = 512;
constexpr int PIX = FH * FW;               // 60800 = 475 * 128
constexpr size_t PLANE = (size_t)PIX;
constexpr size_t NHWC_ELEMS = (size_t)N_IMG * PLANE * CN;
constexpr size_t NHWC_BF16_BYTES = NHWC_ELEMS * sizeof(unsigned short);

constexpr int CT = 64;    // channel tile
constexpr int PT = 128;   // pixel tile (60800 % 128 == 0)

__device__ __forceinline__ unsigned short f2bf_rne(float f) {
    unsigned int u = __float_as_uint(f);
    unsigned int r = (u + 0x7FFFu + ((u >> 16) & 1u)) >> 16;  // RNE
    return (unsigned short)r;
}

// ---------------- tiled transpose NCHW fp32 -> NHWC bf16 ----------------
// grid (PIX/PT = 475, N_IMG*CN/CT = 8), 256 threads.
// Phase 1: thread (q = t&31, r = t>>5) loads float4 of channel c = r + 8i
//   at pixel offset 4q. Per wave instruction (fixed i): 2 x 512-B bursts.
// Phase 2: thread (cq = t&7, p0 = t>>3) packs 8 channels -> uint4 at
//   pixel p = p0 + 32*i2; full-128B-line NHWC writes. Row stride 129
//   keeps phase-2 LDS reads at 2 lanes/bank (free).
__global__ __launch_bounds__(256) void nchw_to_nhwc_bf16_tiled(
    const float* __restrict__ in, unsigned short* __restrict__ ws)
{
    const int pbase = blockIdx.x * PT;
    const int nc = blockIdx.y;           // 0..7
    const int n = nc >> 2;
    const int cbase = (nc & 3) * CT;

    __shared__ float tile[CT][PT + 1];   // 64 x 129 fp32 = 33,024 B

    {
        const int q = threadIdx.x & 31;  // float4 slot within pixel row
        const int r = threadIdx.x >> 5;  // 0..7
        const float* src = in + ((size_t)n * CN + cbase) * PLANE + pbase + 4 * q;
#pragma unroll
        for (int i = 0; i < 8; ++i) {
            const int c = r + 8 * i;
            const float4 v = *(const float4*)(src + (size_t)c * PLANE);
            tile[c][4 * q + 0] = v.x;
            tile[c][4 * q + 1] = v.y;
            tile[c][4 * q + 2] = v.z;
            tile[c][4 * q + 3] = v.w;
        }
    }
    __syncthreads();
    {
        const int cq = threadIdx.x & 7;  // channel octet: channels 8cq..8cq+7
        const int p0 = threadIdx.x >> 3; // 0..31
        unsigned short* dstbase =
            ws + ((size_t)n * PLANE + pbase) * CN + cbase + 8 * cq;
#pragma unroll
        for (int i2 = 0; i2 < 4; ++i2) {
            const int p = p0 + 32 * i2;
            uint4 pk;
            pk.x = (unsigned int)f2bf_rne(tile[8 * cq + 0][p]) |
                   ((unsigned int)f2bf_rne(tile[8 * cq + 1][p]) << 16);
            pk.y = (unsigned int)f2bf_rne(tile[8 * cq + 2][p]) |
                   ((unsigned int)f2bf_rne(tile[8 * cq + 3][p]) << 16);
            pk.z = (unsigned int)f2bf_rne(tile[8 * cq + 4][p]) |
                   ((unsigned int)f2bf_rne(tile[8 * cq + 5][p]) << 16);
            pk.w = (unsigned int)f2bf_rne(tile[8 * cq + 6][p]) |
                   ((unsigned int)f2bf_rne(tile[8 * cq + 7][p]) << 16);
            *(uint4*)(dstbase + (size_t)p * CN) = pk;
        }
    }
}

// ---------------- gather on NHWC bf16: (roi, ph) blocks, XCD-swizzled ----
// 1-D grid of 3584; decode so all 7 ph of a roi share (id % 8) => same XCD.
// 128 threads (2 waves); thread t owns channel pair 2t,2t+1. 28 samples x
// 4 corners, fully compile-time unrolled -> 112 independent loads/thread.
__global__ __launch_bounds__(128) void roi_align_nhwc_bf16(
    const unsigned short* __restrict__ ws,
    const float* __restrict__ rois,
    float* __restrict__ out)
{
    const int b = blockIdx.x;
    const int x = b & 7;                 // XCD residue
    const int s_id = b >> 3;             // 0..447
    const int r  = (s_id / 7) * 8 + x;   // roi
    const int ph = s_id % 7;             // output row
    const int t  = threadIdx.x;          // channel pair: 2t, 2t+1

    __shared__ float s_roi[5];
    __shared__ int   s_off[28][4];       // BYTE offsets into NHWC bf16 image
    __shared__ float s_w[28][4];
    __shared__ int   s_b;

    if (t < 5) s_roi[t] = rois[r * 5 + t];
    __syncthreads();

    if (t < 28) {
        const int s  = t;
        const int gy = s / 14;
        const int ix = s % 14;
        const float x1 = s_roi[1] * SPATIAL_SCALE - 0.5f;
        const float y1 = s_roi[2] * SPATIAL_SCALE - 0.5f;
        const float x2 = s_roi[3] * SPATIAL_SCALE - 0.5f;
        const float y2 = s_roi[4] * SPATIAL_SCALE - 0.5f;
        const float bin_w = (x2 - x1) / OUT_W;
        const float bin_h = (y2 - y1) / OUT_H;
        const float y = y1 + ph * bin_h + (gy + 0.5f) * bin_h * 0.5f;
        const float xf = x1 + (ix >> 1) * bin_w + ((ix & 1) + 0.5f) * bin_w * 0.5f;
        const float validf =
            (y > -1.0f && y < (float)FH && xf > -1.0f && xf < (float)FW) ? 1.0f : 0.0f;
        const float yc = fminf(fmaxf(y, 0.0f), (float)(FH - 1));
        const float xc = fminf(fmaxf(xf, 0.0f), (float)(FW - 1));
        const int y0 = (int)floorf(yc);
        const int x0 = (int)floorf(xc);
        const int y1i = min(y0 + 1, FH - 1);
        const int x1i = min(x0 + 1, FW - 1);
        const float ly = yc - (float)y0;
        const float lx = xc - (float)x0;
        const float hy = 1.0f - ly;
        const float hx = 1.0f - lx;
        s_off[s][0] = ((y0  * FW + x0 ) * CN) * 2;
        s_off[s][1] = ((y0  * FW + x1i) * CN) * 2;
        s_off[s][2] = ((y1i * FW + x0 ) * CN) * 2;
        s_off[s][3] = ((y1i * FW + x1i) * CN) * 2;
        s_w[s][0] = hy * hx * validf;
        s_w[s][1] = hy * lx * validf;
        s_w[s][2] = ly * hx * validf;
        s_w[s][3] = ly * lx * validf;
    }
    if (t == 0) s_b = (int)s_roi[0];
    __syncthreads();

    const char* base =
        (const char*)(ws + (size_t)s_b * (PLANE * CN) + 2 * t);

    float acc0[OUT_W] = {0.f, 0.f, 0.f, 0.f, 0.f, 0.f, 0.f};
    float acc1[OUT_W] = {0.f, 0.f, 0.f, 0.f, 0.f, 0.f, 0.f};
#pragma unroll
    for (int s = 0; s < 28; ++s) {
        const int pw = (s % 14) >> 1;
#pragma unroll
        for (int k = 0; k < 4; ++k) {
            const unsigned int u = *(const unsigned int*)(base + s_off[s][k]);
            const float f0 = __uint_as_float(u << 16);
            const float f1 = __uint_as_float(u & 0xFFFF0000u);
            const float w = s_w[s][k];
            acc0[pw] = fmaf(w, f0, acc0[pw]);
            acc1[pw] = fmaf(w, f1, acc1[pw]);
        }
    }

    const size_t outbase = ((size_t)r * CN + 2 * t) * (OUT_H * OUT_W) + (size_t)ph * OUT_W;
#pragma unroll
    for (int pw = 0; pw < OUT_W; ++pw) {
        out[outbase + pw] = acc0[pw] * 0.25f;
        out[outbase + (OUT_H * OUT_W) + pw] = acc1[pw] * 0.25f;
    }
}

// ---------------- fallback: NCHW gather (round-1 kernel) ----------------
__global__ __launch_bounds__(256) void roi_align_nchw(
    const float* __restrict__ feat,
    const float* __restrict__ rois,
    float* __restrict__ out)
{
    const int r  = blockIdx.x;
    const int ph = blockIdx.y;
    const int c  = threadIdx.x;

    __shared__ float s_roi[5];
    __shared__ int   s_off[28][4];
    __shared__ float s_w[28][4];
    __shared__ int   s_b;

    if (threadIdx.x < 5) s_roi[threadIdx.x] = rois[r * 5 + threadIdx.x];
    __syncthreads();

    if (threadIdx.x < 28) {
        const int s  = threadIdx.x;
        const int gy = s / 14;
        const int ix = s % 14;
        const float x1 = s_roi[1] * SPATIAL_SCALE - 0.5f;
        const float y1 = s_roi[2] * SPATIAL_SCALE - 0.5f;
        const float x2 = s_roi[3] * SPATIAL_SCALE - 0.5f;
        const float y2 = s_roi[4] * SPATIAL_SCALE - 0.5f;
        const float bin_w = (x2 - x1) / OUT_W;
        const float bin_h = (y2 - y1) / OUT_H;
        const float y = y1 + ph * bin_h + (gy + 0.5f) * bin_h * 0.5f;
        const float xf = x1 + (ix >> 1) * bin_w + ((ix & 1) + 0.5f) * bin_w * 0.5f;
        const float validf =
            (y > -1.0f && y < (float)FH && xf > -1.0f && xf < (float)FW) ? 1.0f : 0.0f;
        const float yc = fminf(fmaxf(y, 0.0f), (float)(FH - 1));
        const float xc = fminf(fmaxf(xf, 0.0f), (float)(FW - 1));
        const int y0 = (int)floorf(yc);
        const int x0 = (int)floorf(xc);
        const int y1i = min(y0 + 1, FH - 1);
        const int x1i = min(x0 + 1, FW - 1);
        const float ly = yc - (float)y0;
        const float lx = xc - (float)x0;
        const float hy = 1.0f - ly;
        const float hx = 1.0f - lx;
        s_off[s][0] = y0  * FW + x0;
        s_off[s][1] = y0  * FW + x1i;
        s_off[s][2] = y1i * FW + x0;
        s_off[s][3] = y1i * FW + x1i;
        s_w[s][0] = hy * hx * validf;
        s_w[s][1] = hy * lx * validf;
        s_w[s][2] = ly * hx * validf;
        s_w[s][3] = ly * lx * validf;
    }
    if (threadIdx.x == 0) s_b = (int)s_roi[0];
    __syncthreads();

    const float* base = feat + ((size_t)s_b * CN + c) * PLANE;

    float acc[OUT_W] = {0.f, 0.f, 0.f, 0.f, 0.f, 0.f, 0.f};
#pragma unroll
    for (int s = 0; s < 28; ++s) {
        const float v0 = base[s_off[s][0]];
        const float v1 = base[s_off[s][1]];
        const float v2 = base[s_off[s][2]];
        const float v3 = base[s_off[s][3]];
        acc[(s % 14) >> 1] += s_w[s][0] * v0 + s_w[s][1] * v1 +
                              s_w[s][2] * v2 + s_w[s][3] * v3;
    }

    const size_t outbase = ((size_t)r * CN + c) * (OUT_H * OUT_W) + (size_t)ph * OUT_W;
#pragma unroll
    for (int pw = 0; pw < OUT_W; ++pw) {
        out[outbase + pw] = acc[pw] * 0.25f;
    }
}

extern "C" void kernel_launch(void* const* d_in, const int* in_sizes, int n_in,
                              void* d_out, int out_size, void* d_ws, size_t ws_size,
                              hipStream_t stream) {
    const float* feat = (const float*)d_in[0];
    const float* rois = (const float*)d_in[1];
    float* out = (float*)d_out;

    if (ws_size >= NHWC_BF16_BYTES) {
        unsigned short* ws = (unsigned short*)d_ws;
        dim3 tgrid(PIX / PT, (N_IMG * CN) / CT, 1);  // 475 x 8 = 3800 blocks
        nchw_to_nhwc_bf16_tiled<<<tgrid, dim3(256, 1, 1), 0, stream>>>(feat, ws);
        roi_align_nhwc_bf16<<<dim3(N_ROIS * OUT_H, 1, 1), dim3(128, 1, 1), 0, stream>>>(
            ws, rois, out);
    } else {
        dim3 grid(N_ROIS, OUT_H, 1);
        roi_align_nchw<<<grid, dim3(256, 1, 1), 0, stream>>>(feat, rois, out);
    }
}